// Round 13
// baseline (223.729 us; speedup 1.0000x reference)
//
#include <hip/hip_runtime.h>

// x:(1,64,64,768) -> n=4096 tokens, DIM=768, 12 heads x 64 dim
#define NTOK 4096
#define DIMD 768
#define NHD  12
#define HDD  64
#define DK   800   // extended K: 768 x | 4 lora-q | 4 lora-v | 24 zero

typedef float  f32x2  __attribute__((ext_vector_type(2)));
typedef float  f32x4  __attribute__((ext_vector_type(4)));
typedef float  f32x16 __attribute__((ext_vector_type(16)));
typedef short  s16x8  __attribute__((ext_vector_type(8)));

#define MFMA16(a, b, c) __builtin_amdgcn_mfma_f32_16x16x32_bf16(a, b, c, 0, 0, 0)
#define MFMA32(a, b, c) __builtin_amdgcn_mfma_f32_32x32x16_bf16(a, b, c, 0, 0, 0)

#if __has_builtin(__builtin_amdgcn_exp2f)
#define EXP2(x) __builtin_amdgcn_exp2f(x)
#else
#define EXP2(x) exp2f(x)
#endif

__device__ inline short f2b(float f) {  // fp32 -> bf16 RNE
  unsigned u = __float_as_uint(f);
  u += 0x7FFFu + ((u >> 16) & 1u);
  return (short)(u >> 16);
}
__device__ inline float b2f(short s) {
  return __uint_as_float(((unsigned)(unsigned short)s) << 16);
}
__device__ inline void gl_lds16(const short* g, short* l) {
  __builtin_amdgcn_global_load_lds(
      (const __attribute__((address_space(1))) unsigned int*)g,
      (__attribute__((address_space(3))) unsigned int*)l, 16, 0, 0);
}

// ws layout (float units):
//   xe    @0         bf16 [4096][800]
//   we    @1638400   bf16 [2304][800]
//   wpb   @2560000   bf16 [768][768]
//   qkvb  @2854912   bf16 [3][12][4096][64]  (V third unused)
//   vtb   @7573504   bf16 [12][64][4096]  (keys pi-permuted within 16-groups)
//   attnb @9146368   bf16 [4096][768]

// ---------------------------------------------------------------------------
// Kernel A (merged prep): extended weights we[2304][800], wpb[768][768],
// xe[4096][800] = [bf16(x) | 0.25*x@Aq^T | 0.25*x@Av^T | 0].
__global__ __launch_bounds__(64)
void k_prep(const float* __restrict__ Wqkv, const float* __restrict__ Bq,
            const float* __restrict__ Bv, const float* __restrict__ Wp,
            const float* __restrict__ x, const float* __restrict__ Aq,
            const float* __restrict__ Av, short* __restrict__ we,
            short* __restrict__ wpb, short* __restrict__ xe) {
  const int j = blockIdx.x;
  const int l = threadIdx.x;
  if (j < 2304) {
#pragma unroll
    for (int k = 0; k < 12; ++k)
      we[(size_t)j * DK + l + 64 * k] = f2b(Wqkv[(size_t)j * DIMD + l + 64 * k]);
    if (l < 32) {
      int c = 768 + l;
      short v = 0;
      if (l < 4) {
        if (j < 768) v = f2b(Bq[j * 4 + l]);
      } else if (l < 8) {
        if (j >= 1536) v = f2b(Bv[(j - 1536) * 4 + (l - 4)]);
      }
      we[(size_t)j * DK + c] = v;
    }
  } else if (j < 3072) {
    const int jr = j - 2304;
#pragma unroll
    for (int k = 0; k < 12; ++k)
      wpb[(size_t)jr * DIMD + l + 64 * k] =
          f2b(Wp[(size_t)jr * DIMD + l + 64 * k]);
  } else {
    const int i = j - 3072;
    float xv[12];
#pragma unroll
    for (int k = 0; k < 12; ++k) xv[k] = x[(size_t)i * DIMD + l + 64 * k];
#pragma unroll
    for (int k = 0; k < 12; ++k)
      xe[(size_t)i * DK + l + 64 * k] = f2b(xv[k]);
    float a8[8];
#pragma unroll
    for (int o = 0; o < 8; ++o) {
      const float* A = (o < 4) ? (Aq + o * DIMD) : (Av + (o - 4) * DIMD);
      float acc = 0.f;
#pragma unroll
      for (int k = 0; k < 12; ++k) acc = fmaf(xv[k], A[l + 64 * k], acc);
#pragma unroll
      for (int off = 32; off; off >>= 1) acc += __shfl_xor(acc, off, 64);
      a8[o] = acc;
    }
    if (l < 32) {
      float v = 0.f;
#pragma unroll
      for (int o = 0; o < 8; ++o)
        if (l == o) v = 0.25f * a8[o];
      xe[(size_t)i * DK + 768 + l] = (l < 8) ? f2b(v) : (short)0;
    }
  }
}

// ---------------------------------------------------------------------------
// Kernel 2: bf16 MFMA qkv GEMM over extended K=800 (LoRA folded in).
// 64x128 tiles, grid (18, 64) = 1152 blocks for load balance (4.5 blk/CU).
// Wave w covers N cols [w*32, w*32+32). q/k -> qkvb; v -> vtb (transposed+pi).
__global__ __launch_bounds__(256)
void k_qkv(const short* __restrict__ xe, const short* __restrict__ we,
           const float* __restrict__ bqkv, short* __restrict__ qkvb,
           short* __restrict__ vtb) {
  const int j0 = blockIdx.x * 128;
  const int i0 = blockIdx.y * 64;
  __shared__ short As[64 * 32];
  __shared__ short Bs[128 * 32];
  __shared__ short Cs[64 * 130];
  const int t = threadIdx.x, lane = t & 63, w = t >> 6;
  const int l15 = lane & 15, quad = lane >> 4;

  f32x4 acc[4][2];
#pragma unroll
  for (int a = 0; a < 4; ++a)
#pragma unroll
    for (int b = 0; b < 2; ++b) acc[a][b] = (f32x4){0.f, 0.f, 0.f, 0.f};

  for (int kk = 0; kk < DK; kk += 32) {
    __syncthreads();
    {  // A: 64 rows x 4 chunks = 256 slots (1/thread)
      int c = w * 64 + lane;
      gl_lds16(xe + (size_t)(i0 + (c >> 2)) * DK + kk + (c & 3) * 8,
               &As[(w * 64) * 8]);
    }
#pragma unroll
    for (int rep = 0; rep < 2; ++rep) {  // B: 128 rows x 4 chunks = 512 slots
      int c = rep * 256 + w * 64 + lane;
      gl_lds16(we + (size_t)(j0 + (c >> 2)) * DK + kk + (c & 3) * 8,
               &Bs[(rep * 256 + w * 64) * 8]);
    }
    __syncthreads();
    s16x8 af[4], bf[2];
#pragma unroll
    for (int mt = 0; mt < 4; ++mt)
      af[mt] = *(const s16x8*)&As[(mt * 16 + l15) * 32 + quad * 8];
#pragma unroll
    for (int nt = 0; nt < 2; ++nt)
      bf[nt] = *(const s16x8*)&Bs[(w * 32 + nt * 16 + l15) * 32 + quad * 8];
#pragma unroll
    for (int mt = 0; mt < 4; ++mt)
#pragma unroll
      for (int nt = 0; nt < 2; ++nt)
        acc[mt][nt] = MFMA16(af[mt], bf[nt], acc[mt][nt]);
  }

  const int which = j0 / DIMD;  // 768 = 6*128, so constant per block
  float bj[2];
#pragma unroll
  for (int nt = 0; nt < 2; ++nt) bj[nt] = bqkv[j0 + w * 32 + nt * 16 + l15];

#pragma unroll
  for (int mt = 0; mt < 4; ++mt)
#pragma unroll
    for (int r = 0; r < 4; ++r) {
      const int row = mt * 16 + quad * 4 + r;
#pragma unroll
      for (int nt = 0; nt < 2; ++nt) {
        const int col = w * 32 + nt * 16 + l15;
        Cs[row * 130 + col] = f2b(acc[mt][nt][r] + bj[nt]);
      }
    }
  __syncthreads();
  const int base_head = (j0 - which * DIMD) >> 6;
  if (which != 2) {
    // q/k: coalesced row stores. 64 rows x 16 chunks = 1024 slots.
#pragma unroll
    for (int rp = 0; rp < 4; ++rp) {
      int f = t + 256 * rp;
      int row = f >> 4, ch = f & 15;
      int head = base_head + (ch >> 3);
      int ddb = (ch & 7) * 8;
      s16x8 v = *(const s16x8*)&Cs[row * 130 + ch * 8];
      *(s16x8*)&qkvb[(((size_t)which * NHD + head) * NTOK + i0 + row) * HDD + ddb] = v;
    }
  } else {
    // v: transposed + pi-permuted store into vtb[head][d][n].
    // 128 dcols x 8 n-chunks = 1024 slots.
#pragma unroll
    for (int rp = 0; rp < 4; ++rp) {
      int f = t + 256 * rp;
      int dcol = f >> 3, n8 = (f & 7) * 8;
      unsigned wds[4];
#pragma unroll
      for (int m = 0; m < 4; ++m) {
        int s0 = n8 + 2 * m, s1 = s0 + 1;
        int sr0 = (s0 & 0x70) | ((((s0 >> 2) & 3) == 1 ? 2 : ((s0 >> 2) & 3) == 2 ? 1 : ((s0 >> 2) & 3)) << 2) | (s0 & 3);
        int sr1 = (s1 & 0x70) | ((((s1 >> 2) & 3) == 1 ? 2 : ((s1 >> 2) & 3) == 2 ? 1 : ((s1 >> 2) & 3)) << 2) | (s1 & 3);
        unsigned lo = (unsigned short)Cs[sr0 * 130 + dcol];
        unsigned hi = (unsigned short)Cs[sr1 * 130 + dcol];
        wds[m] = lo | (hi << 16);
      }
      short* dst = vtb + ((size_t)(base_head * 64) + dcol) * NTOK + i0 + n8;
      *(int4*)dst = *(int4*)&wds[0];
    }
  }
}

// ---------------------------------------------------------------------------
// Kernel 4: monolithic 32x32x16-MFMA flash attention (r9 structure: swapped
// operands S^T/O^T, DMA double-buffered staging, permuted-Vt PV, packed-f32
// softmax + raw v_exp_f32). grid (64 qblocks, 12 heads), 4 waves.
// LDS shorts: K0@0, K1@4096, V0@8192, V1@12288, bHb@16384..20480 (log2e folded).
__global__ __launch_bounds__(256)
void k_attn7(const short* __restrict__ qkvb, const short* __restrict__ vtb,
             const float* __restrict__ relh, const float* __restrict__ relw,
             short* __restrict__ attnb) {
  const int head = blockIdx.y;
  const int hq = blockIdx.x;
  const int n0 = hq * 64;

  __shared__ short sm[20480];
  short* smb = sm;

  const short* qg  = qkvb + (size_t)(0 * NHD + head) * NTOK * HDD;
  const short* kg  = qkvb + (size_t)(1 * NHD + head) * NTOK * HDD;
  const short* vtg = vtb + (size_t)head * HDD * NTOK;

  const int t = threadIdx.x;
  const int w = t >> 6, lane = t & 63;
  const int l31 = lane & 31, h = lane >> 5;
  const int kh = w >> 1, qh = w & 1;
  const int q = qh * 32 + l31;

  // DMA slot: (row, chunk ^ (row&7))
  const int slot = w * 64 + lane;
  const int krow = slot >> 3;
  const int kcol = ((slot & 7) ^ (krow & 7)) * 8;
  const short* gK0 = kg + (size_t)krow * HDD + kcol;
  const short* gK1 = gK0 + 32 * HDD;
  const short* gV0 = vtg + (size_t)krow * NTOK + kcol;
  const short* gV1 = gV0 + (size_t)32 * NTOK;

  // Q B-fragments (persist)
  s16x8 qb[4];
#pragma unroll
  for (int s = 0; s < 4; ++s)
    qb[s] = *(const s16x8*)&qg[(size_t)(n0 + q) * HDD + s * 16 + 8 * h];

  // ---- prologue: RW -> overlay ----
#pragma unroll
  for (int rp = 0; rp < 4; ++rp) {
    int f = t + 256 * rp;
    int d = f >> 3, c = (f & 7) * 8;
    float4 v0 = make_float4(0, 0, 0, 0), v1 = v0;
    if (d < 127) {
      const float* s_ = relw + (size_t)d * HDD + c;
      v0 = *(const float4*)s_; v1 = *(const float4*)(s_ + 4);
    }
    short4 b0, b1;
    b0.x = f2b(v0.x); b0.y = f2b(v0.y); b0.z = f2b(v0.z); b0.w = f2b(v0.w);
    b1.x = f2b(v1.x); b1.y = f2b(v1.y); b1.z = f2b(v1.z); b1.w = f2b(v1.w);
    *(short4*)&smb[d * 72 + c] = b0;
    *(short4*)&smb[d * 72 + c + 4] = b1;
  }
  __syncthreads();

  // M^T = RW @ Q^T (log2e folded at store)
  f32x16 mc0 = (f32x16)(0.f), mc1 = (f32x16)(0.f);
#pragma unroll
  for (int s = 0; s < 4; ++s) {
    s16x8 a0 = *(const s16x8*)&smb[((kh * 2) * 32 + l31) * 72 + s * 16 + 8 * h];
    s16x8 a1 = *(const s16x8*)&smb[((kh * 2 + 1) * 32 + l31) * 72 + s * 16 + 8 * h];
    mc0 = MFMA32(a0, qb[s], mc0);
    mc1 = MFMA32(a1, qb[s], mc1);
  }
  __syncthreads();
#pragma unroll
  for (int reg = 0; reg < 16; ++reg) {
    int dl = (reg & 3) + 8 * (reg >> 2) + 4 * h;
    smb[(kh * 64 + dl) * 64 + q] = f2b(mc0[reg] * 1.44269504f);
    smb[(kh * 64 + 32 + dl) * 64 + q] = f2b(mc1[reg] * 1.44269504f);
  }
  __syncthreads();

  f32x2 bw2[8];
#pragma unroll
  for (int i = 0; i < 8; ++i)
#pragma unroll
    for (int p = 0; p < 2; ++p) {
      int reg = 2 * i + p;
      int kl64 = kh * 32 + (reg & 3) + 8 * (reg >> 2) + 4 * h;
      int dneed = q - kl64 + 63;  // [0,126]
      bw2[i][p] = b2f(smb[dneed * 64 + q]);
    }
  __syncthreads();

  // RH -> overlay
#pragma unroll
  for (int rp = 0; rp < 2; ++rp) {
    int f = t + 256 * rp;
    int kt = f >> 3, c = (f & 7) * 8;
    const float* s_ = relh + (size_t)(hq + 63 - kt) * HDD + c;
    float4 v0 = *(const float4*)s_, v1 = *(const float4*)(s_ + 4);
    short4 b0, b1;
    b0.x = f2b(v0.x); b0.y = f2b(v0.y); b0.z = f2b(v0.z); b0.w = f2b(v0.w);
    b1.x = f2b(v1.x); b1.y = f2b(v1.y); b1.z = f2b(v1.z); b1.w = f2b(v1.w);
    *(short4*)&smb[kt * 72 + c] = b0;
    *(short4*)&smb[kt * 72 + c + 4] = b1;
  }
  __syncthreads();

  // bH^T = RH @ Q^T -> bHb @16384 (log2e prefolded)
  f32x16 hc = (f32x16)(0.f);
#pragma unroll
  for (int s = 0; s < 4; ++s) {
    s16x8 a = *(const s16x8*)&smb[(kh * 32 + l31) * 72 + s * 16 + 8 * h];
    hc = MFMA32(a, qb[s], hc);
  }
#pragma unroll
  for (int reg = 0; reg < 16; ++reg) {
    int ktl = kh * 32 + (reg & 3) + 8 * (reg >> 2) + 4 * h;
    smb[16384 + ktl * 64 + q] = f2b(hc[reg] * 1.44269504f);
  }
  __syncthreads();  // RH reads done; bHb published; DMA may write [0,16384)

  // bootstrap: tile 0 -> K0, V0
  gl_lds16(gK0, smb + 0 + w * 512);
  gl_lds16(gK1, smb + 2048 + w * 512);
  gl_lds16(gV0, smb + 8192 + w * 512);
  gl_lds16(gV1, smb + 8192 + 2048 + w * 512);
  gK0 += 4096; gK1 += 4096;
  gV0 += 64; gV1 += 64;

  // read bases
  int baseS[4], baseV[2];
#pragma unroll
  for (int s = 0; s < 4; ++s)
    baseS[s] = (kh * 32 + l31) * 64 + (((2 * s + h) ^ (l31 & 7)) * 8);
#pragma unroll
  for (int s2 = 0; s2 < 2; ++s2)
    baseV[s2] = l31 * 64 + (((kh * 4 + s2 * 2 + h) ^ (l31 & 7)) * 8);

  f32x2 ps2 = (f32x2)(0.f);
  f32x16 oc0 = (f32x16)(0.f), oc1 = (f32x16)(0.f);

#define ATTN_ITER(KT, KSRC, VSRC, KDST, VDST)                                  \
  {                                                                            \
    __syncthreads();                                                           \
    if ((KT) < 63) {                                                           \
      gl_lds16(gK0, smb + (KDST) + w * 512);                                   \
      gl_lds16(gK1, smb + (KDST) + 2048 + w * 512);                            \
      gl_lds16(gV0, smb + (VDST) + w * 512);                                   \
      gl_lds16(gV1, smb + (VDST) + 2048 + w * 512);                            \
      gK0 += 4096; gK1 += 4096; gV0 += 64; gV1 += 64;                          \
    }                                                                          \
    f32x16 sc_ = (f32x16)(0.f);                                                \
    _Pragma("unroll") for (int s = 0; s < 4; ++s) {                            \
      s16x8 a = *(const s16x8*)&smb[(KSRC) + baseS[s]];                        \
      sc_ = MFMA32(a, qb[s], sc_);                                             \
    }                                                                          \
    float bhl2 = b2f(smb[16384 + (KT) * 64 + q]);                              \
    unsigned pk[8];                                                            \
    _Pragma("unroll") for (int i = 0; i < 8; ++i) {                            \
      f32x2 s2;                                                                \
      s2[0] = sc_[2 * i]; s2[1] = sc_[2 * i + 1];                              \
      f32x2 r = s2 * 0.18033688f + (bw2[i] + bhl2);                            \
      float e0 = EXP2(r[0]);                                                   \
      float e1 = EXP2(r[1]);                                                   \
      f32x2 e2; e2[0] = e0; e2[1] = e1;                                        \
      ps2 += e2;                                                               \
      pk[i] = __builtin_amdgcn_perm(__float_as_uint(e1),                       \
                                    __float_as_uint(e0), 0x07060302u);         \
    }                                                                          \
    _Pragma("unroll") for (int s2i = 0; s2i < 2; ++s2i) {                      \
      union { unsigned u[4]; s16x8 v; } B;                                     \
      B.u[0] = pk[4 * s2i + 0];                                                \
      B.u[1] = pk[4 * s2i + 1];                                                \
      B.u[2] = pk[4 * s2i + 2];                                                \
      B.u[3] = pk[4 * s2i + 3];                                                \
      s16x8 a0 = *(const s16x8*)&smb[(VSRC) + baseV[s2i]];                     \
      s16x8 a1 = *(const s16x8*)&smb[(VSRC) + 2048 + baseV[s2i]];              \
      oc0 = MFMA32(a0, B.v, oc0);                                              \
      oc1 = MFMA32(a1, B.v, oc1);                                              \
    }                                                                          \
  }

  for (int k2 = 0; k2 < 32; ++k2) {
    ATTN_ITER(2 * k2,     0,    8192,  4096, 12288);
    ATTN_ITER(2 * k2 + 1, 4096, 12288, 0,    8192);
  }
#undef ATTN_ITER

  // ---- epilogue: combine kh halves, normalize, transpose, store ----
  __syncthreads();
  float ps = ps2[0] + ps2[1];
  float* obuf = (float*)smb;          // [64][66] floats @0
  float* psb  = (float*)smb + 4224;
  short* tbuf = smb + 8576;           // [64][66] shorts
  ps += __shfl_xor(ps, 32, 64);
  if (kh == 1) {
#pragma unroll
    for (int reg = 0; reg < 16; ++reg) {
      int dl = (reg & 3) + 8 * (reg >> 2) + 4 * h;
      obuf[dl * 66 + q] = oc0[reg];
      obuf[(32 + dl) * 66 + q] = oc1[reg];
    }
    if (lane < 32) psb[q] = ps;
  }
  __syncthreads();
  if (kh == 0) {
    float inv = 1.f / (ps + psb[q]);
#pragma unroll
    for (int reg = 0; reg < 16; ++reg) {
      int dl = (reg & 3) + 8 * (reg >> 2) + 4 * h;
      tbuf[dl * 66 + q] = f2b((oc0[reg] + obuf[dl * 66 + q]) * inv);
      tbuf[(32 + dl) * 66 + q] = f2b((oc1[reg] + obuf[(32 + dl) * 66 + q]) * inv);
    }
  }
  __syncthreads();
  {
    int qq = t >> 2, seg = t & 3;
    unsigned wds[8];
#pragma unroll
    for (int m = 0; m < 8; ++m) {
      unsigned lo = (unsigned short)tbuf[(seg * 16 + 2 * m) * 66 + qq];
      unsigned hi = (unsigned short)tbuf[(seg * 16 + 2 * m + 1) * 66 + qq];
      wds[m] = lo | (hi << 16);
    }
    short* dst = attnb + (size_t)(n0 + qq) * DIMD + head * 64 + seg * 16;
    *(int4*)dst = *(int4*)&wds[0];
    *(int4*)(dst + 8) = *(int4*)&wds[4];
  }
}

// ---------------------------------------------------------------------------
// Kernel 5: bf16 MFMA proj: out = attn @ Wp^T + bp (fp32 out).
// 64x64 tiles, grid (12, 64) = 768 blocks (3 blk/CU); waves 2x2 of 32x32.
__global__ __launch_bounds__(256)
void k_proj(const short* __restrict__ ab, const short* __restrict__ wpb,
            const float* __restrict__ bp, float* __restrict__ out) {
  const int j0 = blockIdx.x * 64;
  const int i0 = blockIdx.y * 64;
  __shared__ short As[64 * 32];
  __shared__ short Bs[64 * 32];
  const int t = threadIdx.x, lane = t & 63, w = t >> 6;
  const int l15 = lane & 15, quad = lane >> 4;
  const int wm = w >> 1, wn = w & 1;

  f32x4 acc[2][2];
#pragma unroll
  for (int a = 0; a < 2; ++a)
#pragma unroll
    for (int b = 0; b < 2; ++b) acc[a][b] = (f32x4){0.f, 0.f, 0.f, 0.f};

  for (int kk = 0; kk < DIMD; kk += 32) {
    __syncthreads();
    {
      int c = w * 64 + lane;
      gl_lds16(ab + (size_t)(i0 + (c >> 2)) * DIMD + kk + (c & 3) * 8,
               &As[(w * 64) * 8]);
      gl_lds16(wpb + (size_t)(j0 + (c >> 2)) * DIMD + kk + (c & 3) * 8,
               &Bs[(w * 64) * 8]);
    }
    __syncthreads();
    s16x8 af[2], bf[2];
#pragma unroll
    for (int mt = 0; mt < 2; ++mt)
      af[mt] = *(const s16x8*)&As[(wm * 32 + mt * 16 + l15) * 32 + quad * 8];
#pragma unroll
    for (int nt = 0; nt < 2; ++nt)
      bf[nt] = *(const s16x8*)&Bs[(wn * 32 + nt * 16 + l15) * 32 + quad * 8];
#pragma unroll
    for (int mt = 0; mt < 2; ++mt)
#pragma unroll
      for (int nt = 0; nt < 2; ++nt)
        acc[mt][nt] = MFMA16(af[mt], bf[nt], acc[mt][nt]);
  }

#pragma unroll
  for (int mt = 0; mt < 2; ++mt)
#pragma unroll
    for (int r = 0; r < 4; ++r) {
      const int i = i0 + wm * 32 + mt * 16 + quad * 4 + r;
#pragma unroll
      for (int nt = 0; nt < 2; ++nt) {
        const int j = j0 + wn * 32 + nt * 16 + l15;
        out[(size_t)i * DIMD + j] = acc[mt][nt][r] + bp[j];
      }
    }
}

// ---------------------------------------------------------------------------
extern "C" void kernel_launch(void* const* d_in, const int* in_sizes, int n_in,
                              void* d_out, int out_size, void* d_ws, size_t ws_size,
                              hipStream_t stream) {
  (void)in_sizes; (void)n_in; (void)out_size; (void)ws_size;
  const float* x    = (const float*)d_in[0];
  const float* Wqkv = (const float*)d_in[1];
  const float* bqkv = (const float*)d_in[2];
  const float* Aq   = (const float*)d_in[3];
  const float* Bq   = (const float*)d_in[4];
  const float* Av   = (const float*)d_in[5];
  const float* Bv   = (const float*)d_in[6];
  const float* relh = (const float*)d_in[7];
  const float* relw = (const float*)d_in[8];
  const float* Wp   = (const float*)d_in[9];
  const float* bp   = (const float*)d_in[10];
  float* out = (float*)d_out;

  float* ws = (float*)d_ws;
  short* xe    = (short*)(ws);
  short* we    = (short*)(ws + 1638400);
  short* wpb   = (short*)(ws + 2560000);
  short* qkvb  = (short*)(ws + 2854912);
  short* vtb   = (short*)(ws + 7573504);
  short* attnb = (short*)(ws + 9146368);

  k_prep<<<dim3(7168), dim3(64), 0, stream>>>(Wqkv, Bq, Bv, Wp, x, Aq, Av,
                                              we, wpb, xe);
  k_qkv<<<dim3(18, 64), dim3(256), 0, stream>>>(xe, we, bqkv, qkvb, vtb);
  k_attn7<<<dim3(64, NHD), dim3(256), 0, stream>>>(qkvb, vtb, relh, relw, attnb);
  k_proj<<<dim3(12, 64), dim3(256), 0, stream>>>(attnb, wpb, bp, out);
}

// Round 14
// 221.006 us; speedup vs baseline: 1.0123x; 1.0123x over previous
//
#include <hip/hip_runtime.h>

// x:(1,64,64,768) -> n=4096 tokens, DIM=768, 12 heads x 64 dim
#define NTOK 4096
#define DIMD 768
#define NHD  12
#define HDD  64
#define DK   800   // extended K: 768 x | 4 lora-q | 4 lora-v | 24 zero

typedef float  f32x2  __attribute__((ext_vector_type(2)));
typedef float  f32x4  __attribute__((ext_vector_type(4)));
typedef float  f32x16 __attribute__((ext_vector_type(16)));
typedef short  s16x8  __attribute__((ext_vector_type(8)));

#define MFMA16(a, b, c) __builtin_amdgcn_mfma_f32_16x16x32_bf16(a, b, c, 0, 0, 0)
#define MFMA32(a, b, c) __builtin_amdgcn_mfma_f32_32x32x16_bf16(a, b, c, 0, 0, 0)

#if __has_builtin(__builtin_amdgcn_exp2f)
#define EXP2(x) __builtin_amdgcn_exp2f(x)
#else
#define EXP2(x) exp2f(x)
#endif

__device__ inline short f2b(float f) {  // fp32 -> bf16 RNE
  unsigned u = __float_as_uint(f);
  u += 0x7FFFu + ((u >> 16) & 1u);
  return (short)(u >> 16);
}
__device__ inline float b2f(short s) {
  return __uint_as_float(((unsigned)(unsigned short)s) << 16);
}
__device__ inline short4 f2b4(float4 v) {
  short4 b;
  b.x = f2b(v.x); b.y = f2b(v.y); b.z = f2b(v.z); b.w = f2b(v.w);
  return b;
}
__device__ inline void gl_lds16(const short* g, short* l) {
  __builtin_amdgcn_global_load_lds(
      (const __attribute__((address_space(1))) unsigned int*)g,
      (__attribute__((address_space(3))) unsigned int*)l, 16, 0, 0);
}

// ws layout (float units):
//   xe    @0         bf16 [4096][800]
//   we    @1638400   bf16 [2304][800]
//   wpb   @2560000   bf16 [768][768]
//   qkvb  @2854912   bf16 [3][12][4096][64]  (V third unused)
//   vtb   @7573504   bf16 [12][64][4096]  (keys pi-permuted within 16-groups)
//   attnb @9146368   bf16 [4096][768]

// ---------------------------------------------------------------------------
// Kernel A (merged prep): extended weights we[2304][800] (vectorized),
// wpb[768][768] (vectorized), xe[4096][800] = [bf16(x) | 0.25*x@A^T | 0].
__global__ __launch_bounds__(64)
void k_prep(const float* __restrict__ Wqkv, const float* __restrict__ Bq,
            const float* __restrict__ Bv, const float* __restrict__ Wp,
            const float* __restrict__ x, const float* __restrict__ Aq,
            const float* __restrict__ Av, short* __restrict__ we,
            short* __restrict__ wpb, short* __restrict__ xe) {
  const int j = blockIdx.x;
  const int l = threadIdx.x;
  if (j < 2304) {
    // 192 float4 groups per row, 3 per thread
#pragma unroll
    for (int g = 0; g < 3; ++g) {
      int c4 = (l + 64 * g) * 4;
      float4 v = *(const float4*)&Wqkv[(size_t)j * DIMD + c4];
      *(short4*)&we[(size_t)j * DK + c4] = f2b4(v);
    }
    if (l < 32) {
      int c = 768 + l;
      short v = 0;
      if (l < 4) {
        if (j < 768) v = f2b(Bq[j * 4 + l]);
      } else if (l < 8) {
        if (j >= 1536) v = f2b(Bv[(j - 1536) * 4 + (l - 4)]);
      }
      we[(size_t)j * DK + c] = v;
    }
  } else if (j < 3072) {
    const int jr = j - 2304;
#pragma unroll
    for (int g = 0; g < 3; ++g) {
      int c4 = (l + 64 * g) * 4;
      float4 v = *(const float4*)&Wp[(size_t)jr * DIMD + c4];
      *(short4*)&wpb[(size_t)jr * DIMD + c4] = f2b4(v);
    }
  } else {
    const int i = j - 3072;
    float xv[12];
#pragma unroll
    for (int k = 0; k < 12; ++k) xv[k] = x[(size_t)i * DIMD + l + 64 * k];
#pragma unroll
    for (int k = 0; k < 12; ++k)
      xe[(size_t)i * DK + l + 64 * k] = f2b(xv[k]);
    float a8[8];
#pragma unroll
    for (int o = 0; o < 8; ++o) {
      const float* A = (o < 4) ? (Aq + o * DIMD) : (Av + (o - 4) * DIMD);
      float acc = 0.f;
#pragma unroll
      for (int k = 0; k < 12; ++k) acc = fmaf(xv[k], A[l + 64 * k], acc);
#pragma unroll
      for (int off = 32; off; off >>= 1) acc += __shfl_xor(acc, off, 64);
      a8[o] = acc;
    }
    if (l < 32) {
      float v = 0.f;
#pragma unroll
      for (int o = 0; o < 8; ++o)
        if (l == o) v = 0.25f * a8[o];
      xe[(size_t)i * DK + 768 + l] = (l < 8) ? f2b(v) : (short)0;
    }
  }
}

// ---------------------------------------------------------------------------
// Kernel 2: bf16 MFMA qkv GEMM over extended K=800 (LoRA folded in).
// 128x128 tiles (r9 best), grid (18, 32). q/k thirds -> qkvb[which][head][n][d];
// v third -> vtb[head][d][n] (transposed + pi-permuted).
__global__ __launch_bounds__(256)
void k_qkv(const short* __restrict__ xe, const short* __restrict__ we,
           const float* __restrict__ bqkv, short* __restrict__ qkvb,
           short* __restrict__ vtb) {
  const int j0 = blockIdx.x * 128;
  const int i0 = blockIdx.y * 128;
  __shared__ short As[128 * 32];
  __shared__ short Bs[128 * 32];
  __shared__ short Cs[128 * 130];
  const int t = threadIdx.x, lane = t & 63, w = t >> 6;
  const int l15 = lane & 15, quad = lane >> 4;
  const int wm = w >> 1, wn = w & 1;

  f32x4 acc[4][4];
#pragma unroll
  for (int a = 0; a < 4; ++a)
#pragma unroll
    for (int b = 0; b < 4; ++b) acc[a][b] = (f32x4){0.f, 0.f, 0.f, 0.f};

  for (int kk = 0; kk < DK; kk += 32) {
    __syncthreads();
#pragma unroll
    for (int rep = 0; rep < 2; ++rep) {
      int c = rep * 256 + w * 64 + lane;
      gl_lds16(xe + (size_t)(i0 + (c >> 2)) * DK + kk + (c & 3) * 8,
               &As[(rep * 256 + w * 64) * 8]);
      gl_lds16(we + (size_t)(j0 + (c >> 2)) * DK + kk + (c & 3) * 8,
               &Bs[(rep * 256 + w * 64) * 8]);
    }
    __syncthreads();
    s16x8 af[4], bf[4];
#pragma unroll
    for (int mt = 0; mt < 4; ++mt)
      af[mt] = *(const s16x8*)&As[(wm * 64 + mt * 16 + l15) * 32 + quad * 8];
#pragma unroll
    for (int nt = 0; nt < 4; ++nt)
      bf[nt] = *(const s16x8*)&Bs[(wn * 64 + nt * 16 + l15) * 32 + quad * 8];
#pragma unroll
    for (int mt = 0; mt < 4; ++mt)
#pragma unroll
      for (int nt = 0; nt < 4; ++nt)
        acc[mt][nt] = MFMA16(af[mt], bf[nt], acc[mt][nt]);
  }

  const int which = j0 / DIMD;
  float bj[4];
#pragma unroll
  for (int nt = 0; nt < 4; ++nt) bj[nt] = bqkv[j0 + wn * 64 + nt * 16 + l15];

#pragma unroll
  for (int mt = 0; mt < 4; ++mt)
#pragma unroll
    for (int r = 0; r < 4; ++r) {
      const int row = wm * 64 + mt * 16 + quad * 4 + r;
#pragma unroll
      for (int nt = 0; nt < 4; ++nt) {
        const int col = wn * 64 + nt * 16 + l15;
        Cs[row * 130 + col] = f2b(acc[mt][nt][r] + bj[nt]);
      }
    }
  __syncthreads();
  const int base_head = (j0 - which * DIMD) >> 6;
  if (which != 2) {
#pragma unroll
    for (int rp = 0; rp < 8; ++rp) {
      int f = t + 256 * rp;
      int row = f >> 4, ch = f & 15;
      int head = base_head + (ch >> 3);
      int ddb = (ch & 7) * 8;
      s16x8 v = *(const s16x8*)&Cs[row * 130 + ch * 8];
      *(s16x8*)&qkvb[(((size_t)which * NHD + head) * NTOK + i0 + row) * HDD + ddb] = v;
    }
  } else {
    // v: transposed + pi-permuted store into vtb[head][d][n]
#pragma unroll
    for (int rp = 0; rp < 8; ++rp) {
      int f = t + 256 * rp;
      int dcol = f >> 4, n8 = (f & 15) * 8;
      unsigned wds[4];
#pragma unroll
      for (int m = 0; m < 4; ++m) {
        int s0 = n8 + 2 * m, s1 = s0 + 1;
        int sr0 = (s0 & 0x70) | ((((s0 >> 2) & 3) == 1 ? 2 : ((s0 >> 2) & 3) == 2 ? 1 : ((s0 >> 2) & 3)) << 2) | (s0 & 3);
        int sr1 = (s1 & 0x70) | ((((s1 >> 2) & 3) == 1 ? 2 : ((s1 >> 2) & 3) == 2 ? 1 : ((s1 >> 2) & 3)) << 2) | (s1 & 3);
        unsigned lo = (unsigned short)Cs[sr0 * 130 + dcol];
        unsigned hi = (unsigned short)Cs[sr1 * 130 + dcol];
        wds[m] = lo | (hi << 16);
      }
      short* dst = vtb + ((size_t)(base_head * 64) + dcol) * NTOK + i0 + n8;
      *(int4*)dst = *(int4*)&wds[0];
    }
  }
}

// ---------------------------------------------------------------------------
// Kernel 4: monolithic 32x32x16-MFMA flash attention (r9 structure: swapped
// operands S^T/O^T, DMA double-buffered staging, permuted-Vt PV, packed-f32
// softmax + raw v_exp_f32). grid (64 qblocks, 12 heads), 4 waves.
// LDS shorts: K0@0, K1@4096, V0@8192, V1@12288, bHb@16384..20480 (log2e folded).
__global__ __launch_bounds__(256)
void k_attn7(const short* __restrict__ qkvb, const short* __restrict__ vtb,
             const float* __restrict__ relh, const float* __restrict__ relw,
             short* __restrict__ attnb) {
  const int head = blockIdx.y;
  const int hq = blockIdx.x;
  const int n0 = hq * 64;

  __shared__ short sm[20480];
  short* smb = sm;

  const short* qg  = qkvb + (size_t)(0 * NHD + head) * NTOK * HDD;
  const short* kg  = qkvb + (size_t)(1 * NHD + head) * NTOK * HDD;
  const short* vtg = vtb + (size_t)head * HDD * NTOK;

  const int t = threadIdx.x;
  const int w = t >> 6, lane = t & 63;
  const int l31 = lane & 31, h = lane >> 5;
  const int kh = w >> 1, qh = w & 1;
  const int q = qh * 32 + l31;

  // DMA slot: (row, chunk ^ (row&7))
  const int slot = w * 64 + lane;
  const int krow = slot >> 3;
  const int kcol = ((slot & 7) ^ (krow & 7)) * 8;
  const short* gK0 = kg + (size_t)krow * HDD + kcol;
  const short* gK1 = gK0 + 32 * HDD;
  const short* gV0 = vtg + (size_t)krow * NTOK + kcol;
  const short* gV1 = gV0 + (size_t)32 * NTOK;

  // Q B-fragments (persist)
  s16x8 qb[4];
#pragma unroll
  for (int s = 0; s < 4; ++s)
    qb[s] = *(const s16x8*)&qg[(size_t)(n0 + q) * HDD + s * 16 + 8 * h];

  // ---- prologue: RW -> overlay ----
#pragma unroll
  for (int rp = 0; rp < 4; ++rp) {
    int f = t + 256 * rp;
    int d = f >> 3, c = (f & 7) * 8;
    float4 v0 = make_float4(0, 0, 0, 0), v1 = v0;
    if (d < 127) {
      const float* s_ = relw + (size_t)d * HDD + c;
      v0 = *(const float4*)s_; v1 = *(const float4*)(s_ + 4);
    }
    *(short4*)&smb[d * 72 + c] = f2b4(v0);
    *(short4*)&smb[d * 72 + c + 4] = f2b4(v1);
  }
  __syncthreads();

  // M^T = RW @ Q^T (log2e folded at store)
  f32x16 mc0 = (f32x16)(0.f), mc1 = (f32x16)(0.f);
#pragma unroll
  for (int s = 0; s < 4; ++s) {
    s16x8 a0 = *(const s16x8*)&smb[((kh * 2) * 32 + l31) * 72 + s * 16 + 8 * h];
    s16x8 a1 = *(const s16x8*)&smb[((kh * 2 + 1) * 32 + l31) * 72 + s * 16 + 8 * h];
    mc0 = MFMA32(a0, qb[s], mc0);
    mc1 = MFMA32(a1, qb[s], mc1);
  }
  __syncthreads();
#pragma unroll
  for (int reg = 0; reg < 16; ++reg) {
    int dl = (reg & 3) + 8 * (reg >> 2) + 4 * h;
    smb[(kh * 64 + dl) * 64 + q] = f2b(mc0[reg] * 1.44269504f);
    smb[(kh * 64 + 32 + dl) * 64 + q] = f2b(mc1[reg] * 1.44269504f);
  }
  __syncthreads();

  f32x2 bw2[8];
#pragma unroll
  for (int i = 0; i < 8; ++i)
#pragma unroll
    for (int p = 0; p < 2; ++p) {
      int reg = 2 * i + p;
      int kl64 = kh * 32 + (reg & 3) + 8 * (reg >> 2) + 4 * h;
      int dneed = q - kl64 + 63;  // [0,126]
      bw2[i][p] = b2f(smb[dneed * 64 + q]);
    }
  __syncthreads();

  // RH -> overlay
#pragma unroll
  for (int rp = 0; rp < 2; ++rp) {
    int f = t + 256 * rp;
    int kt = f >> 3, c = (f & 7) * 8;
    const float* s_ = relh + (size_t)(hq + 63 - kt) * HDD + c;
    float4 v0 = *(const float4*)s_, v1 = *(const float4*)(s_ + 4);
    *(short4*)&smb[kt * 72 + c] = f2b4(v0);
    *(short4*)&smb[kt * 72 + c + 4] = f2b4(v1);
  }
  __syncthreads();

  // bH^T = RH @ Q^T -> bHb @16384 (log2e prefolded)
  f32x16 hc = (f32x16)(0.f);
#pragma unroll
  for (int s = 0; s < 4; ++s) {
    s16x8 a = *(const s16x8*)&smb[(kh * 32 + l31) * 72 + s * 16 + 8 * h];
    hc = MFMA32(a, qb[s], hc);
  }
#pragma unroll
  for (int reg = 0; reg < 16; ++reg) {
    int ktl = kh * 32 + (reg & 3) + 8 * (reg >> 2) + 4 * h;
    smb[16384 + ktl * 64 + q] = f2b(hc[reg] * 1.44269504f);
  }
  __syncthreads();  // RH reads done; bHb published; DMA may write [0,16384)

  // bootstrap: tile 0 -> K0, V0
  gl_lds16(gK0, smb + 0 + w * 512);
  gl_lds16(gK1, smb + 2048 + w * 512);
  gl_lds16(gV0, smb + 8192 + w * 512);
  gl_lds16(gV1, smb + 8192 + 2048 + w * 512);
  gK0 += 4096; gK1 += 4096;
  gV0 += 64; gV1 += 64;

  // read bases
  int baseS[4], baseV[2];
#pragma unroll
  for (int s = 0; s < 4; ++s)
    baseS[s] = (kh * 32 + l31) * 64 + (((2 * s + h) ^ (l31 & 7)) * 8);
#pragma unroll
  for (int s2 = 0; s2 < 2; ++s2)
    baseV[s2] = l31 * 64 + (((kh * 4 + s2 * 2 + h) ^ (l31 & 7)) * 8);

  f32x2 ps2 = (f32x2)(0.f);
  f32x16 oc0 = (f32x16)(0.f), oc1 = (f32x16)(0.f);

#define ATTN_ITER(KT, KSRC, VSRC, KDST, VDST)                                  \
  {                                                                            \
    __syncthreads();                                                           \
    if ((KT) < 63) {                                                           \
      gl_lds16(gK0, smb + (KDST) + w * 512);                                   \
      gl_lds16(gK1, smb + (KDST) + 2048 + w * 512);                            \
      gl_lds16(gV0, smb + (VDST) + w * 512);                                   \
      gl_lds16(gV1, smb + (VDST) + 2048 + w * 512);                            \
      gK0 += 4096; gK1 += 4096; gV0 += 64; gV1 += 64;                          \
    }                                                                          \
    f32x16 sc_ = (f32x16)(0.f);                                                \
    _Pragma("unroll") for (int s = 0; s < 4; ++s) {                            \
      s16x8 a = *(const s16x8*)&smb[(KSRC) + baseS[s]];                        \
      sc_ = MFMA32(a, qb[s], sc_);                                             \
    }                                                                          \
    float bhl2 = b2f(smb[16384 + (KT) * 64 + q]);                              \
    unsigned pk[8];                                                            \
    _Pragma("unroll") for (int i = 0; i < 8; ++i) {                            \
      f32x2 s2;                                                                \
      s2[0] = sc_[2 * i]; s2[1] = sc_[2 * i + 1];                              \
      f32x2 r = s2 * 0.18033688f + (bw2[i] + bhl2);                            \
      float e0 = EXP2(r[0]);                                                   \
      float e1 = EXP2(r[1]);                                                   \
      f32x2 e2; e2[0] = e0; e2[1] = e1;                                        \
      ps2 += e2;                                                               \
      pk[i] = __builtin_amdgcn_perm(__float_as_uint(e1),                       \
                                    __float_as_uint(e0), 0x07060302u);         \
    }                                                                          \
    _Pragma("unroll") for (int s2i = 0; s2i < 2; ++s2i) {                      \
      union { unsigned u[4]; s16x8 v; } B;                                     \
      B.u[0] = pk[4 * s2i + 0];                                                \
      B.u[1] = pk[4 * s2i + 1];                                                \
      B.u[2] = pk[4 * s2i + 2];                                                \
      B.u[3] = pk[4 * s2i + 3];                                                \
      s16x8 a0 = *(const s16x8*)&smb[(VSRC) + baseV[s2i]];                     \
      s16x8 a1 = *(const s16x8*)&smb[(VSRC) + 2048 + baseV[s2i]];              \
      oc0 = MFMA32(a0, B.v, oc0);                                              \
      oc1 = MFMA32(a1, B.v, oc1);                                              \
    }                                                                          \
  }

  for (int k2 = 0; k2 < 32; ++k2) {
    ATTN_ITER(2 * k2,     0,    8192,  4096, 12288);
    ATTN_ITER(2 * k2 + 1, 4096, 12288, 0,    8192);
  }
#undef ATTN_ITER

  // ---- epilogue: combine kh halves, normalize, transpose, store ----
  __syncthreads();
  float ps = ps2[0] + ps2[1];
  float* obuf = (float*)smb;          // [64][66] floats @0
  float* psb  = (float*)smb + 4224;
  short* tbuf = smb + 8576;           // [64][66] shorts
  ps += __shfl_xor(ps, 32, 64);
  if (kh == 1) {
#pragma unroll
    for (int reg = 0; reg < 16; ++reg) {
      int dl = (reg & 3) + 8 * (reg >> 2) + 4 * h;
      obuf[dl * 66 + q] = oc0[reg];
      obuf[(32 + dl) * 66 + q] = oc1[reg];
    }
    if (lane < 32) psb[q] = ps;
  }
  __syncthreads();
  if (kh == 0) {
    float inv = 1.f / (ps + psb[q]);
#pragma unroll
    for (int reg = 0; reg < 16; ++reg) {
      int dl = (reg & 3) + 8 * (reg >> 2) + 4 * h;
      tbuf[dl * 66 + q] = f2b((oc0[reg] + obuf[dl * 66 + q]) * inv);
      tbuf[(32 + dl) * 66 + q] = f2b((oc1[reg] + obuf[(32 + dl) * 66 + q]) * inv);
    }
  }
  __syncthreads();
  {
    int qq = t >> 2, seg = t & 3;
    unsigned wds[8];
#pragma unroll
    for (int m = 0; m < 8; ++m) {
      unsigned lo = (unsigned short)tbuf[(seg * 16 + 2 * m) * 66 + qq];
      unsigned hi = (unsigned short)tbuf[(seg * 16 + 2 * m + 1) * 66 + qq];
      wds[m] = lo | (hi << 16);
    }
    short* dst = attnb + (size_t)(n0 + qq) * DIMD + head * 64 + seg * 16;
    *(int4*)dst = *(int4*)&wds[0];
    *(int4*)(dst + 8) = *(int4*)&wds[4];
  }
}

// ---------------------------------------------------------------------------
// Kernel 5: bf16 MFMA proj: out = attn @ Wp^T + bp (fp32 out).
// 64x64 tiles, grid (12, 64) = 768 blocks (even 3 blk/CU); waves 2x2 of 32x32.
__global__ __launch_bounds__(256)
void k_proj(const short* __restrict__ ab, const short* __restrict__ wpb,
            const float* __restrict__ bp, float* __restrict__ out) {
  const int j0 = blockIdx.x * 64;
  const int i0 = blockIdx.y * 64;
  __shared__ short As[64 * 32];
  __shared__ short Bs[64 * 32];
  const int t = threadIdx.x, lane = t & 63, w = t >> 6;
  const int l15 = lane & 15, quad = lane >> 4;
  const int wm = w >> 1, wn = w & 1;

  f32x4 acc[2][2];
#pragma unroll
  for (int a = 0; a < 2; ++a)
#pragma unroll
    for (int b = 0; b < 2; ++b) acc[a][b] = (f32x4){0.f, 0.f, 0.f, 0.f};

  for (int kk = 0; kk < DIMD; kk += 32) {
    __syncthreads();
    {
      int c = w * 64 + lane;
      gl_lds16(ab + (size_t)(i0 + (c >> 2)) * DIMD + kk + (c & 3) * 8,
               &As[(w * 64) * 8]);
      gl_lds16(wpb + (size_t)(j0 + (c >> 2)) * DIMD + kk + (c & 3) * 8,
               &Bs[(w * 64) * 8]);
    }
    __syncthreads();
    s16x8 af[2], bf[2];
#pragma unroll
    for (int mt = 0; mt < 2; ++mt)
      af[mt] = *(const s16x8*)&As[(wm * 32 + mt * 16 + l15) * 32 + quad * 8];
#pragma unroll
    for (int nt = 0; nt < 2; ++nt)
      bf[nt] = *(const s16x8*)&Bs[(wn * 32 + nt * 16 + l15) * 32 + quad * 8];
#pragma unroll
    for (int mt = 0; mt < 2; ++mt)
#pragma unroll
      for (int nt = 0; nt < 2; ++nt)
        acc[mt][nt] = MFMA16(af[mt], bf[nt], acc[mt][nt]);
  }

#pragma unroll
  for (int mt = 0; mt < 2; ++mt)
#pragma unroll
    for (int r = 0; r < 4; ++r) {
      const int i = i0 + wm * 32 + mt * 16 + quad * 4 + r;
#pragma unroll
      for (int nt = 0; nt < 2; ++nt) {
        const int j = j0 + wn * 32 + nt * 16 + l15;
        out[(size_t)i * DIMD + j] = acc[mt][nt][r] + bp[j];
      }
    }
}

// ---------------------------------------------------------------------------
extern "C" void kernel_launch(void* const* d_in, const int* in_sizes, int n_in,
                              void* d_out, int out_size, void* d_ws, size_t ws_size,
                              hipStream_t stream) {
  (void)in_sizes; (void)n_in; (void)out_size; (void)ws_size;
  const float* x    = (const float*)d_in[0];
  const float* Wqkv = (const float*)d_in[1];
  const float* bqkv = (const float*)d_in[2];
  const float* Aq   = (const float*)d_in[3];
  const float* Bq   = (const float*)d_in[4];
  const float* Av   = (const float*)d_in[5];
  const float* Bv   = (const float*)d_in[6];
  const float* relh = (const float*)d_in[7];
  const float* relw = (const float*)d_in[8];
  const float* Wp   = (const float*)d_in[9];
  const float* bp   = (const float*)d_in[10];
  float* out = (float*)d_out;

  float* ws = (float*)d_ws;
  short* xe    = (short*)(ws);
  short* we    = (short*)(ws + 1638400);
  short* wpb   = (short*)(ws + 2560000);
  short* qkvb  = (short*)(ws + 2854912);
  short* vtb   = (short*)(ws + 7573504);
  short* attnb = (short*)(ws + 9146368);

  k_prep<<<dim3(7168), dim3(64), 0, stream>>>(Wqkv, Bq, Bv, Wp, x, Aq, Av,
                                              we, wpb, xe);
  k_qkv<<<dim3(18, 32), dim3(256), 0, stream>>>(xe, we, bqkv, qkvb, vtb);
  k_attn7<<<dim3(64, NHD), dim3(256), 0, stream>>>(qkvb, vtb, relh, relw, attnb);
  k_proj<<<dim3(12, 64), dim3(256), 0, stream>>>(attnb, wpb, bp, out);
}